// Round 6
// baseline (394.386 us; speedup 1.0000x reference)
//
#include <hip/hip_runtime.h>
#include <math.h>

// Problem constants
#define NSEQ 4
#define BATCH 256
#define T 64
#define FIN 32
#define S 512
#define KTOT 544     // FIN + S unified k-dimension

// Pipelined decomposition: 4 lanes concurrent (lane i lags i-1 by 1 step).
// Per lane: 16 groups x 16 rows, 4 slice-WGs x 128 cols. 4*16*4 = 256 WGs.
// NT=512 (8 waves). Wave -> one 16x16 col-tile, 17 K-tiles of
// mfma_f32_16x16x32_bf16, SPLIT-BF16 (hi+lo residual, 3 products).
//
// R6: TAG-IN-DATA handshake. Ring stores h as packed split-bf16 u32
// (hi16|lo16) with the 2 LSBs of lo carrying an epoch tag
// tag(t) = ((t>>2)%3)+1 (0 = zero-init; alias distance 12 steps > max
// pipeline skew 7; perturbation ~2^-15 relative). Consumers poll the DATA
// rows directly in a retry loop and accept when all tags match -> ONE MALL
// round-trip from store-visibility to use; the stamp publish + tight poll
// leave the critical chain. Stamps remain only as LOOSE slot-reuse guards
// (own >= t-2, cons >= t-3, first checked at t=4; 3 steps of slack) and for
// the final output reduction. These also guarantee no producer can
// overwrite a slot a consumer retry-loop still waits on (a sibling at step
// t+3 would need own-stamp >= t+1, impossible while we are at step t).
// Ring write-regions are zero-initialized per run by their owner WG
// (re-poisoned ws can never false-accept: poison tag bits are checked
// against nonzero tags only after zeroing, and zeros have tag 0);
// poison-keyed FLAG_MAGIC init gates all of it. ALL traffic sc0 sc1 (MALL)
// -- no sc0-dirty-line replay hazard (R2-R4 lesson).
#define NT 512
#define NWG 256
#define RPG 16
#define SW 128       // cols per slice-WG
#define DEPTH 4
#define NKT 17       // K-tiles of 32 (544/32)

// ws float offsets (content is POISON at launch - never read before init)
#define RING_SZ  (4ull * DEPTH * BATCH * S)        // 8 MB state ring
#define OUTP_OFF RING_SZ                            // [gid][sl][16] partials
#define CTL_OFF  (RING_SZ + 16384ull)               // ctl area

#define FLAG_MAGIC 0x13572468u

#define AS 552   // A-LDS row stride in bf16 elems (544 + 8 pad)

typedef __attribute__((ext_vector_type(8))) short short8;      // 8 bf16
typedef __attribute__((ext_vector_type(4))) float f32x4;       // MFMA C/D
typedef __attribute__((ext_vector_type(4))) unsigned u32x4;    // asm 4-dword

// ---- split-bf16: value = hi (truncated bf16) + lo (bf16 of residual) ------
__device__ __forceinline__ unsigned bf_hi(float f) {
  return (__float_as_uint(f) >> 16);
}
__device__ __forceinline__ float bf_hi_f(float f) {
  return __uint_as_float(__float_as_uint(f) & 0xFFFF0000u);
}
// reconstruct f32 from packed (hi16|lo16)
__device__ __forceinline__ float rec_f(unsigned w) {
  return __uint_as_float(w & 0xFFFF0000u) + __uint_as_float(w << 16);
}
__device__ __forceinline__ unsigned umin4(u32x4 v) {
  unsigned a = v[0] < v[1] ? v[0] : v[1];
  unsigned b = v[2] < v[3] ? v[2] : v[3];
  return a < b ? a : b;
}
__device__ __forceinline__ bool alleq4(u32x4 v, unsigned m) {
  return v[0] == m && v[1] == m && v[2] == m && v[3] == m;
}
__device__ __forceinline__ unsigned step_tag(int t) {
  return (unsigned)(((t >> 2) % 3) + 1);
}

// ---- MALL (system scope) coherent I/O: sc0 sc1 everywhere -----------------
__device__ __forceinline__ void cstoreu_glb(unsigned* p, unsigned v) {
  asm volatile("global_store_dword %0, %1, off sc0 sc1" :: "v"(p), "v"(v) : "memory");
}
__device__ __forceinline__ void cstore4_glb(unsigned* p, u32x4 v) {
  asm volatile("global_store_dwordx4 %0, %1, off sc0 sc1" :: "v"(p), "v"(v) : "memory");
}
__device__ __forceinline__ u32x4 cld4_glb(const unsigned* p) {
  u32x4 v;
  asm volatile("global_load_dwordx4 %0, %1, off sc0 sc1\n\ts_waitcnt vmcnt(0)"
               : "=v"(v) : "v"(p) : "memory");
  return v;
}
__device__ __forceinline__ void cld2x4_glb(u32x4* a, u32x4* b,
                                           const unsigned* pa, const unsigned* pb) {
  asm volatile(
      "global_load_dwordx4 %0, %2, off sc0 sc1\n\t"
      "global_load_dwordx4 %1, %3, off sc0 sc1\n\t"
      "s_waitcnt vmcnt(0)"
      : "=&v"(*a), "=&v"(*b) : "v"(pa), "v"(pb) : "memory");
}
__device__ __forceinline__ void cstore1(float* p, float v) {
  asm volatile("global_store_dword %0, %1, off sc0 sc1" :: "v"(p), "v"(v) : "memory");
}
__device__ __forceinline__ float cload1(const float* p) {
  float v;
  asm volatile("global_load_dword %0, %1, off sc0 sc1\n\ts_waitcnt vmcnt(0)"
               : "=v"(v) : "v"(p) : "memory");
  return v;
}
// one tagged row (4 x dwordx4, 512B stride between col-blocks)
__device__ __forceinline__ void cload_rowu(u32x4* d, const unsigned* p) {
  asm volatile(
      "global_load_dwordx4 %0, %4, off sc0 sc1\n\t"
      "global_load_dwordx4 %1, %4, off offset:512 sc0 sc1\n\t"
      "global_load_dwordx4 %2, %4, off offset:1024 sc0 sc1\n\t"
      "global_load_dwordx4 %3, %4, off offset:1536 sc0 sc1\n\t"
      "s_waitcnt vmcnt(0)"
      : "=&v"(d[0]), "=&v"(d[1]), "=&v"(d[2]), "=&v"(d[3])
      : "v"(p) : "memory");
}
__device__ __forceinline__ void cload_row2u(u32x4* h, u32x4* q,
                                            const unsigned* ph, const unsigned* pp) {
  asm volatile(
      "global_load_dwordx4 %0, %8, off sc0 sc1\n\t"
      "global_load_dwordx4 %1, %8, off offset:512 sc0 sc1\n\t"
      "global_load_dwordx4 %2, %8, off offset:1024 sc0 sc1\n\t"
      "global_load_dwordx4 %3, %8, off offset:1536 sc0 sc1\n\t"
      "global_load_dwordx4 %4, %9, off sc0 sc1\n\t"
      "global_load_dwordx4 %5, %9, off offset:512 sc0 sc1\n\t"
      "global_load_dwordx4 %6, %9, off offset:1024 sc0 sc1\n\t"
      "global_load_dwordx4 %7, %9, off offset:1536 sc0 sc1\n\t"
      "s_waitcnt vmcnt(0)"
      : "=&v"(h[0]), "=&v"(h[1]), "=&v"(h[2]), "=&v"(h[3]),
        "=&v"(q[0]), "=&v"(q[1]), "=&v"(q[2]), "=&v"(q[3])
      : "v"(ph), "v"(pp) : "memory");
}

// ctl layout (dwords, stride 64 per gid; stamps and flags on different
// 128B lines):
//   ctl + gid*64 + [0..3]      : per-slice step stamps (one 128B line)
//   ctl + gid*64 + 32 + [0..3] : per-slice init flags (next 128B line)

extern "C" __global__ void __launch_bounds__(NT, 1)
rnn_mfma(const float* __restrict__ x,      // [4][256][64][32]
         const float* __restrict__ Wcell,  // [4][544][512]
         const float* __restrict__ bcell,  // [4][512]
         const float* __restrict__ Wcomb,  // [3][1024]
         const float* __restrict__ bcomb,  // [3]
         const float* __restrict__ Wout,   // [512]
         float* __restrict__ out,          // [1024] = [lane][batch]
         float* __restrict__ ws)
{
  // XCD-grouped block mapping (perf heuristic only; correctness is
  // placement-independent: everything goes through MALL).
  const int b    = blockIdx.x;
  const int o    = b >> 3;
  const int grp  = (b & 7) + 8 * (o >> 4);
  const int sub  = o & 15;
  const int lane = sub >> 2;
  const int sl   = sub & 3;
  const int gid  = lane * 16 + grp;
  const int r0 = grp * RPG, sb = sl * SW;
  const int tid = threadIdx.x;

  __shared__ __align__(16) unsigned short A1[RPG * AS];  // 17.3 KB hi [x|hc]
  __shared__ __align__(16) unsigned short A2[RPG * AS];  // 17.3 KB lo
  __shared__ float wg_lds[2 * S];                        //  4.0 KB gate weights
  __shared__ float obuf[128];
  __shared__ float fbuf[64];

  unsigned* uring   = (unsigned*)ws;           // ring as packed u32
  unsigned* ctl     = (unsigned*)(ws + CTL_OFF);
  unsigned* st_own  = ctl + gid * 64;
  unsigned* st_prod = ctl + (gid - 16) * 64;   // valid iff lane>0
  unsigned* st_cons = ctl + (gid + 16) * 64;   // valid iff lane<3
  unsigned* st_mine = st_own + sl;
  unsigned* flg_own  = st_own + 32;
  unsigned* flg_prod = st_prod + 32;
  unsigned* flg_cons = st_cons + 32;
  const unsigned* pc_poll = (lane < 3) ? st_cons : st_own;

  // ---- init: zero own ring write-region (+ stamps by sl0), post flag ----
  {
    const u32x4 z = {0u, 0u, 0u, 0u};
    const int zr = tid >> 5, zc4 = (tid & 31) * 4;
    #pragma unroll
    for (int d = 0; d < DEPTH; ++d) {
      unsigned* p = uring + ((size_t)(lane * DEPTH + d) * BATCH + r0 + zr) * S + sb + zc4;
      cstore4_glb(p, z);
    }
    if (sl == 0 && tid == 0) cstore4_glb(st_own, z);
  }
  asm volatile("s_waitcnt vmcnt(0)" ::: "memory");
  __syncthreads();                 // all zero-stores of this WG drained
  if (tid == 0) {
    cstoreu_glb(flg_own + sl, FLAG_MAGIC);
    // wait for: own gid (4 flags: ring regions + stamps zeroed), producer
    // gid (we read its ring), consumer gid (we read its stamps; it reads us)
    for (;;) {
      bool ok = alleq4(cld4_glb(flg_own), FLAG_MAGIC);
      if (lane > 0) ok &= alleq4(cld4_glb(flg_prod), FLAG_MAGIC);
      if (lane < 3) ok &= alleq4(cld4_glb(flg_cons), FLAG_MAGIC);
      if (ok) break;
      __builtin_amdgcn_s_sleep(2);
    }
  }

  // ---- per-thread constants ----
  const float* Wc = Wcell + (size_t)lane * KTOT * S;
  // MFMA mapping: wave wt (0..7) owns cols [sb+wt*16, +16); within wave:
  //   A-frag: row m = wl&15, k = q*8+j   (q = wl>>4)
  //   B-frag: col n = wl&15, k = q*8+j
  //   C/D:    col  = wl&15, row = q*4+reg
  const int wl = tid & 63, wt = tid >> 6;
  const int bn = wl & 15, q = wl >> 4;
  const int ncol = sb + wt * 16 + bn;
  short8 B1[NKT], B2[NKT];   // split-bf16 weight frags: 136 regs, static
  #pragma unroll
  for (int kt = 0; kt < NKT; ++kt) {
    short8 b1, b2;
    #pragma unroll
    for (int j = 0; j < 8; ++j) {
      const float w = Wc[(size_t)(kt * 32 + q * 8 + j) * S + ncol];
      b1[j] = (short)bf_hi(w);
      b2[j] = (short)bf_hi(w - bf_hi_f(w));
    }
    B1[kt] = b1; B2[kt] = b2;
  }
  const float bcv = bcell[lane * S + ncol];
  const float wov = Wout[ncol];
  for (int idx = tid; idx < 2 * S; idx += NT)
    wg_lds[idx] = (lane > 0) ? Wcomb[(size_t)(lane - 1) * 2 * S + idx] : 0.0f;
  const float bg = (lane > 0) ? bcomb[lane - 1] : 0.0f;
  // stage/gate mapping: 32 threads per row, 16 rows; wave w owns rows 2w,2w+1
  const int grow = tid >> 5, gch = tid & 31;
  __syncthreads();   // gates on tid0's flag wait too

  float oacc[4] = {0.f, 0.f, 0.f, 0.f};

  for (int t = 0; t < T; ++t) {
    // ---- phase A: x stage (per-wave rows) + LOOSE slot-reuse poll --------
    {
      const float f0 = x[(((size_t)lane * BATCH + r0 + grow) * T + t) * FIN + gch];
      A1[grow * AS + gch] = (unsigned short)bf_hi(f0);
      A2[grow * AS + gch] = (unsigned short)bf_hi(f0 - bf_hi_f(f0));
    }
    if (t >= 4) {   // slot t&3 holds h_{t-4}: siblings must be past step
                    // t-3 (stamp >= t-2); consumer past step t-4 (>= t-3)
      for (;;) {
        u32x4 so, sc;
        cld2x4_glb(&so, &sc, st_own, pc_poll);
        bool ok = (umin4(so) >= (unsigned)(t - 2));
        if (lane < 3) ok &= (umin4(sc) >= (unsigned)(t - 3));
        if (ok) break;
        __builtin_amdgcn_s_sleep(1);
      }
    }

    // ---- phase B: tagged ring poll-load + gate + split-stage hc ----------
    {
      const int row = grow;
      const unsigned* hb = uring + ((size_t)(lane * DEPTH + ((t - 1) & 3)) * BATCH + r0 + row) * S + gch * 4;
      const unsigned* pb = uring + ((size_t)((lane - 1) * DEPTH + (t & 3)) * BATCH + r0 + row) * S + gch * 4;
      const unsigned tag_h = step_tag(t - 1);
      const unsigned tag_p = step_tag(t);
      u32x4 hw[4], pw[4];
      if (t > 0) {
        if (lane > 0) {
          for (;;) {
            cload_row2u(hw, pw, hb, pb);
            unsigned bad = 0u;
            #pragma unroll
            for (int j = 0; j < 4; ++j)
              #pragma unroll
              for (int e = 0; e < 4; ++e)
                bad |= ((hw[j][e] & 3u) ^ tag_h) | ((pw[j][e] & 3u) ^ tag_p);
            if (!bad) break;
            __builtin_amdgcn_s_sleep(1);
          }
        } else {
          for (;;) {
            cload_rowu(hw, hb);
            unsigned bad = 0u;
            #pragma unroll
            for (int j = 0; j < 4; ++j)
              #pragma unroll
              for (int e = 0; e < 4; ++e)
                bad |= ((hw[j][e] & 3u) ^ tag_h);
            if (!bad) break;
            __builtin_amdgcn_s_sleep(1);
          }
        }
      } else {
        #pragma unroll
        for (int j = 0; j < 4; ++j) hw[j] = (u32x4){0u, 0u, 0u, 0u};
        if (lane > 0) {
          for (;;) {
            cload_rowu(pw, pb);
            unsigned bad = 0u;
            #pragma unroll
            for (int j = 0; j < 4; ++j)
              #pragma unroll
              for (int e = 0; e < 4; ++e)
                bad |= ((pw[j][e] & 3u) ^ tag_p);
            if (!bad) break;
            __builtin_amdgcn_s_sleep(1);
          }
        }
      }

      if (lane > 0) {
        // gate scalar from reconstructed f32
        float gs = 0.0f;
        #pragma unroll
        for (int j = 0; j < 4; ++j) {
          const float* wh = &wg_lds[j * 128 + gch * 4];
          const float* wp = wh + S;
          #pragma unroll
          for (int e = 0; e < 4; ++e)
            gs += rec_f(hw[j][e]) * wh[e] + rec_f(pw[j][e]) * wp[e];
        }
        gs += __shfl_xor(gs, 1);  gs += __shfl_xor(gs, 2);  gs += __shfl_xor(gs, 4);
        gs += __shfl_xor(gs, 8);  gs += __shfl_xor(gs, 16);  // 32-lane row halves
        const float wgt = 1.0f / (1.0f + __expf(-(gs + bg)));
        #pragma unroll
        for (int j = 0; j < 4; ++j) {
          ushort4 h4, l4;
          #pragma unroll
          for (int e = 0; e < 4; ++e) {
            const float hf = rec_f(hw[j][e]);
            const float pf = rec_f(pw[j][e]);
            const float hc = fmaf(wgt, hf - pf, pf);
            (&h4.x)[e] = (unsigned short)bf_hi(hc);
            (&l4.x)[e] = (unsigned short)bf_hi(hc - bf_hi_f(hc));
          }
          const int ai = row * AS + 32 + j * 128 + gch * 4;
          *(ushort4*)&A1[ai] = h4;
          *(ushort4*)&A2[ai] = l4;
        }
      } else {
        // lane 0: stored value is already split-bf16 -> pure bit-slice stage
        #pragma unroll
        for (int j = 0; j < 4; ++j) {
          ushort4 h4, l4;
          #pragma unroll
          for (int e = 0; e < 4; ++e) {
            (&h4.x)[e] = (unsigned short)(hw[j][e] >> 16);
            (&l4.x)[e] = (unsigned short)(hw[j][e] & 0xFFFFu);
          }
          const int ai = row * AS + 32 + j * 128 + gch * 4;
          *(ushort4*)&A1[ai] = h4;
          *(ushort4*)&A2[ai] = l4;
        }
      }
    }
    __syncthreads();

    // ---- phase C: MFMA 16x16 tile, 17 K-tiles x 3 split products ----------
    f32x4 acc = {0.f, 0.f, 0.f, 0.f};
    {
      const unsigned short* ar1 = &A1[bn * AS + q * 8];
      const unsigned short* ar2 = &A2[bn * AS + q * 8];
      #pragma unroll
      for (int kt = 0; kt < NKT; ++kt) {
        const short8 a1 = *(const short8*)(ar1 + kt * 32);
        const short8 a2 = *(const short8*)(ar2 + kt * 32);
        acc = __builtin_amdgcn_mfma_f32_16x16x32_bf16(a1, B1[kt], acc, 0, 0, 0);
        acc = __builtin_amdgcn_mfma_f32_16x16x32_bf16(a1, B2[kt], acc, 0, 0, 0);
        acc = __builtin_amdgcn_mfma_f32_16x16x32_bf16(a2, B1[kt], acc, 0, 0, 0);
      }
    }

    // ---- epilogue: +bias, tanh, tagged split-bf16 ring store -------------
    unsigned* uslot = uring + ((size_t)(lane * DEPTH + (t & 3)) * BATCH + r0) * S + sb;
    const unsigned tg = step_tag(t);
    #pragma unroll
    for (int reg = 0; reg < 4; ++reg) {
      const float s2 = acc[reg] + bcv;
      const float aa = fabsf(s2), ee = __expf(2.0f * aa);
      const float tv = copysignf(1.0f - 2.0f / (ee + 1.0f), s2);
      const unsigned hi = bf_hi(tv);
      const unsigned lo = (bf_hi(tv - bf_hi_f(tv)) & 0xFFFCu) | tg;
      cstoreu_glb(uslot + (size_t)(q * 4 + reg) * S + wt * 16 + bn, (hi << 16) | lo);
      if (t == T - 1) oacc[reg] = tv * wov;
    }
    asm volatile("s_waitcnt vmcnt(0)" ::: "memory");  // own stores at MALL
    __syncthreads();  // all threads drained -> safe to stamp + reuse A-LDS
    if (tid == 0) cstoreu_glb(st_mine, (unsigned)(t + 1));
  }

  // ---- output: out[lane*256 + r] = h_T[r] . Wout --------------------------
  #pragma unroll
  for (int reg = 0; reg < 4; ++reg) {
    float v = oacc[reg];
    v += __shfl_xor(v, 1); v += __shfl_xor(v, 2);
    v += __shfl_xor(v, 4); v += __shfl_xor(v, 8);  // sum 16 cols of the tile
    if (bn == 0) obuf[wt * 16 + q * 4 + reg] = v;
  }
  __syncthreads();
  if (tid < 16) {
    float v = 0.0f;
    #pragma unroll
    for (int w = 0; w < 8; ++w) v += obuf[w * 16 + tid];
    cstore1(ws + OUTP_OFF + (size_t)((gid * 4 + sl) * 16 + tid), v);
  }
  asm volatile("s_waitcnt vmcnt(0)" ::: "memory");
  __syncthreads();
  if (tid == 0) cstoreu_glb(st_mine, (unsigned)(T + 1));
  if (sl == 0) {
    if (tid == 0)
      while (umin4(cld4_glb(st_own)) < (unsigned)(T + 1)) __builtin_amdgcn_s_sleep(1);
    __syncthreads();
    if (tid < 64) {
      const int sli = tid >> 4, r = tid & 15;
      fbuf[tid] = cload1(ws + OUTP_OFF + (size_t)((gid * 4 + sli) * 16 + r));
    }
    __syncthreads();
    if (tid < 16) {
      float s2 = 0.f;
      #pragma unroll
      for (int sli = 0; sli < 4; ++sli) s2 += fbuf[sli * 16 + tid];
      out[lane * BATCH + r0 + tid] = s2;
    }
  }
}

extern "C" void kernel_launch(void* const* d_in, const int* in_sizes, int n_in,
                              void* d_out, int out_size, void* d_ws, size_t ws_size,
                              hipStream_t stream) {
  (void)in_sizes; (void)n_in; (void)out_size; (void)ws_size;
  rnn_mfma<<<dim3(NWG), dim3(NT), 0, stream>>>(
      (const float*)d_in[0],   // inputs
      (const float*)d_in[1],   // W_cell
      (const float*)d_in[2],   // b_cell
      (const float*)d_in[3],   // W_comb
      (const float*)d_in[4],   // b_comb
      (const float*)d_in[5],   // W_out
      (float*)d_out,
      (float*)d_ws);
}

// Round 7
// 356.482 us; speedup vs baseline: 1.1063x; 1.1063x over previous
//
#include <hip/hip_runtime.h>
#include <math.h>

// Problem constants
#define NSEQ 4
#define BATCH 256
#define T 64
#define FIN 32
#define S 512
#define KTOT 544     // FIN + S unified k-dimension

// Pipelined decomposition: 4 lanes concurrent (lane i lags i-1 by 1 step).
// Per lane: 16 groups x 16 rows, 4 slice-WGs x 128 cols. 4*16*4 = 256 WGs.
// NT=512 (8 waves). Wave -> one 16x16 col-tile, 17 K-tiles of
// mfma_f32_16x16x32_bf16, SPLIT-BF16 (hi+lo residual, 3 products).
//
// R7: CANARY-IN-BAND handshake (R6's one-RT publish->consume latency without
// R6's per-element VALU tax). Ring stays plain f32. A separate canary array
// canary[lane][slot][grp][row][slice] carries per-(row,slice) step numbers:
//   producer: data stores -> vmcnt(0) -> barrier -> canary = t+1
//             (drain guarantees data visible before canary visible)
//   consumer: ONE fused asm block loads h rows + p rows + h/p canary x4 +
//             own/cons guard stamp lines (12 loads, one vmcnt(0)); accepts
//             when canaries match (h==t, p==t+1) and loose guards hold.
// The stamp-publish + poll-detect + separate-data-load serialization of R5
// collapses to a single MALL round-trip. Guards are RELAXED vs R5:
//   own >= t-2 (sibling slot-reuse: slice at step t-3 reads slot t&3),
//   cons >= t-3 (consumer read of our h_{t-4}),
// removing R5's own>=t sibling lockstep. Canary values are absolute steps
// (no aliasing, unlike R6's 2-bit tags). Canary region zeroed at init under
// the per-slice FLAG_MAGIC protocol (ws is re-poisoned every launch).
// ALL traffic sc0 sc1 (MALL) -- no sc0 dirty-line replay hazard.
#define NT 512
#define NWG 256
#define RPG 16
#define SW 128       // cols per slice-WG
#define DEPTH 4
#define NKT 17       // K-tiles of 32 (544/32)

// ws float offsets (content is POISON at launch - never read before init)
#define RING_SZ  (4ull * DEPTH * BATCH * S)        // 8 MB state ring
#define OUTP_OFF RING_SZ                            // [gid][sl][16] partials
#define CTL_OFF  (RING_SZ + 16384ull)               // ctl + canary area

#define FLAG_MAGIC 0x13572468u

#define AS 552   // A-LDS row stride in bf16 elems (544 + 8 pad)

typedef __attribute__((ext_vector_type(8))) short short8;      // 8 bf16
typedef __attribute__((ext_vector_type(4))) float f32x4;       // MFMA C/D
typedef __attribute__((ext_vector_type(4))) unsigned u32x4;    // asm 4-dword

// ---- split-bf16: value = hi (truncated bf16) + lo (bf16 of residual) ------
__device__ __forceinline__ unsigned short bf_hi(float f) {
  return (unsigned short)(__float_as_uint(f) >> 16);
}
__device__ __forceinline__ float bf_hi_f(float f) {
  return __uint_as_float(__float_as_uint(f) & 0xFFFF0000u);
}
__device__ __forceinline__ unsigned umin4(u32x4 v) {
  unsigned a = v[0] < v[1] ? v[0] : v[1];
  unsigned b = v[2] < v[3] ? v[2] : v[3];
  return a < b ? a : b;
}
__device__ __forceinline__ bool alleq4(u32x4 v, unsigned m) {
  return v[0] == m && v[1] == m && v[2] == m && v[3] == m;
}

// ---- MALL (system scope) coherent I/O: sc0 sc1 everywhere -----------------
__device__ __forceinline__ void cstoreu_glb(unsigned* p, unsigned v) {
  asm volatile("global_store_dword %0, %1, off sc0 sc1" :: "v"(p), "v"(v) : "memory");
}
__device__ __forceinline__ void cstore4_glb(unsigned* p, u32x4 v) {
  asm volatile("global_store_dwordx4 %0, %1, off sc0 sc1" :: "v"(p), "v"(v) : "memory");
}
__device__ __forceinline__ u32x4 cld4_glb(const unsigned* p) {
  u32x4 v;
  asm volatile("global_load_dwordx4 %0, %1, off sc0 sc1\n\ts_waitcnt vmcnt(0)"
               : "=v"(v) : "v"(p) : "memory");
  return v;
}
__device__ __forceinline__ void cstore1(float* p, float v) {
  asm volatile("global_store_dword %0, %1, off sc0 sc1" :: "v"(p), "v"(v) : "memory");
}
__device__ __forceinline__ float cload1(const float* p) {
  float v;
  asm volatile("global_load_dword %0, %1, off sc0 sc1\n\ts_waitcnt vmcnt(0)"
               : "=v"(v) : "v"(p) : "memory");
  return v;
}

// ---- fused consumer loads: data + canaries + guard stamps, ONE vmcnt ------
// lane>0, t>0: h rows + p rows + h-canary + p-canary + own-stamps + cons-stamps
__device__ __forceinline__ void ld_full(float4* h, float4* p, u32x4* hc, u32x4* pc,
                                        u32x4* so, u32x4* sc,
                                        const float* ph, const float* pp,
                                        const unsigned* phc, const unsigned* ppc,
                                        const unsigned* pso, const unsigned* psc) {
  asm volatile(
      "global_load_dwordx4 %0, %12, off sc0 sc1\n\t"
      "global_load_dwordx4 %1, %12, off offset:512 sc0 sc1\n\t"
      "global_load_dwordx4 %2, %12, off offset:1024 sc0 sc1\n\t"
      "global_load_dwordx4 %3, %12, off offset:1536 sc0 sc1\n\t"
      "global_load_dwordx4 %4, %13, off sc0 sc1\n\t"
      "global_load_dwordx4 %5, %13, off offset:512 sc0 sc1\n\t"
      "global_load_dwordx4 %6, %13, off offset:1024 sc0 sc1\n\t"
      "global_load_dwordx4 %7, %13, off offset:1536 sc0 sc1\n\t"
      "global_load_dwordx4 %8, %14, off sc0 sc1\n\t"
      "global_load_dwordx4 %9, %15, off sc0 sc1\n\t"
      "global_load_dwordx4 %10, %16, off sc0 sc1\n\t"
      "global_load_dwordx4 %11, %17, off sc0 sc1\n\t"
      "s_waitcnt vmcnt(0)"
      : "=&v"(h[0]), "=&v"(h[1]), "=&v"(h[2]), "=&v"(h[3]),
        "=&v"(p[0]), "=&v"(p[1]), "=&v"(p[2]), "=&v"(p[3]),
        "=&v"(*hc), "=&v"(*pc), "=&v"(*so), "=&v"(*sc)
      : "v"(ph), "v"(pp), "v"(phc), "v"(ppc), "v"(pso), "v"(psc)
      : "memory");
}
// lane==0, t>0: h rows + h-canary + guard stamps
__device__ __forceinline__ void ld_h(float4* h, u32x4* hc, u32x4* so, u32x4* sc,
                                     const float* ph, const unsigned* phc,
                                     const unsigned* pso, const unsigned* psc) {
  asm volatile(
      "global_load_dwordx4 %0, %7, off sc0 sc1\n\t"
      "global_load_dwordx4 %1, %7, off offset:512 sc0 sc1\n\t"
      "global_load_dwordx4 %2, %7, off offset:1024 sc0 sc1\n\t"
      "global_load_dwordx4 %3, %7, off offset:1536 sc0 sc1\n\t"
      "global_load_dwordx4 %4, %8, off sc0 sc1\n\t"
      "global_load_dwordx4 %5, %9, off sc0 sc1\n\t"
      "global_load_dwordx4 %6, %10, off sc0 sc1\n\t"
      "s_waitcnt vmcnt(0)"
      : "=&v"(h[0]), "=&v"(h[1]), "=&v"(h[2]), "=&v"(h[3]),
        "=&v"(*hc), "=&v"(*so), "=&v"(*sc)
      : "v"(ph), "v"(phc), "v"(pso), "v"(psc)
      : "memory");
}
// lane>0, t==0: p rows + p-canary + guard stamps
__device__ __forceinline__ void ld_p(float4* p, u32x4* pc, u32x4* so, u32x4* sc,
                                     const float* pp, const unsigned* ppc,
                                     const unsigned* pso, const unsigned* psc) {
  asm volatile(
      "global_load_dwordx4 %0, %7, off sc0 sc1\n\t"
      "global_load_dwordx4 %1, %7, off offset:512 sc0 sc1\n\t"
      "global_load_dwordx4 %2, %7, off offset:1024 sc0 sc1\n\t"
      "global_load_dwordx4 %3, %7, off offset:1536 sc0 sc1\n\t"
      "global_load_dwordx4 %4, %8, off sc0 sc1\n\t"
      "global_load_dwordx4 %5, %9, off sc0 sc1\n\t"
      "global_load_dwordx4 %6, %10, off sc0 sc1\n\t"
      "s_waitcnt vmcnt(0)"
      : "=&v"(p[0]), "=&v"(p[1]), "=&v"(p[2]), "=&v"(p[3]),
        "=&v"(*pc), "=&v"(*so), "=&v"(*sc)
      : "v"(pp), "v"(ppc), "v"(pso), "v"(psc)
      : "memory");
}

// ctl layout (dwords, stride 64 per gid; stamps and flags on different
// 128B lines):
//   ctl + gid*64 + [0..3]      : per-slice step stamps (one 128B line)
//   ctl + gid*64 + 32 + [0..3] : per-slice init flags (next 128B line)
//   ctl + 8192                  : canary[lane][slot][grp][row][slice] (64KB)

extern "C" __global__ void __launch_bounds__(NT, 1)
rnn_mfma(const float* __restrict__ x,      // [4][256][64][32]
         const float* __restrict__ Wcell,  // [4][544][512]
         const float* __restrict__ bcell,  // [4][512]
         const float* __restrict__ Wcomb,  // [3][1024]
         const float* __restrict__ bcomb,  // [3]
         const float* __restrict__ Wout,   // [512]
         float* __restrict__ out,          // [1024] = [lane][batch]
         float* __restrict__ ws)
{
  // XCD-grouped block mapping (perf heuristic only; correctness is
  // placement-independent: everything goes through MALL).
  const int b    = blockIdx.x;
  const int o    = b >> 3;
  const int grp  = (b & 7) + 8 * (o >> 4);
  const int sub  = o & 15;
  const int lane = sub >> 2;
  const int sl   = sub & 3;
  const int gid  = lane * 16 + grp;
  const int r0 = grp * RPG, sb = sl * SW;
  const int tid = threadIdx.x;

  __shared__ __align__(16) unsigned short A1[RPG * AS];  // 17.3 KB hi [x|hc]
  __shared__ __align__(16) unsigned short A2[RPG * AS];  // 17.3 KB lo
  __shared__ float wg_lds[2 * S];                        //  4.0 KB gate weights
  __shared__ float obuf[128];
  __shared__ float fbuf[64];

  float* ring = ws;
  unsigned* ctl     = (unsigned*)(ws + CTL_OFF);
  unsigned* st_own  = ctl + gid * 64;
  unsigned* st_cons = ctl + (gid + 16) * 64;   // valid iff lane<3
  unsigned* st_mine = st_own + sl;
  unsigned* flg_own  = st_own + 32;
  unsigned* flg_prod = ctl + (gid - 16) * 64 + 32;  // valid iff lane>0
  unsigned* flg_cons = st_cons + 32;
  unsigned* can = ctl + 8192;                  // canary array base
  const unsigned* psc = (lane < 3) ? st_cons : st_own;

  // ---- init: zero own canary slice + (sl0) stamp line, flag, wait set ----
  if (tid < 64) {
    const int slot = tid >> 4, row = tid & 15;
    cstoreu_glb(can + ((((lane * 4 + slot) * 16 + grp) * 16 + row) * 4 + sl), 0u);
  }
  if (sl == 0 && tid == 0) {
    const u32x4 z = {0u, 0u, 0u, 0u};
    cstore4_glb(st_own, z);
  }
  asm volatile("s_waitcnt vmcnt(0)" ::: "memory");
  __syncthreads();                 // all zero-stores of this WG drained
  if (tid == 0) {
    cstoreu_glb(flg_own + sl, FLAG_MAGIC);
    // wait: own gid (4 canary slices + stamps), producer gid (p-canaries),
    // consumer gid (guard stamp line)
    for (;;) {
      bool ok = alleq4(cld4_glb(flg_own), FLAG_MAGIC);
      if (lane > 0) ok &= alleq4(cld4_glb(flg_prod), FLAG_MAGIC);
      if (lane < 3) ok &= alleq4(cld4_glb(flg_cons), FLAG_MAGIC);
      if (ok) break;
      __builtin_amdgcn_s_sleep(2);
    }
  }

  // ---- per-thread constants ----
  const float* Wc = Wcell + (size_t)lane * KTOT * S;
  // MFMA mapping: wave wt (0..7) owns cols [sb+wt*16, +16); within wave:
  //   A-frag: row m = wl&15, k = q*8+j   (q = wl>>4)
  //   B-frag: col n = wl&15, k = q*8+j
  //   C/D:    col  = wl&15, row = q*4+reg
  const int wl = tid & 63, wt = tid >> 6;
  const int bn = wl & 15, q = wl >> 4;
  const int ncol = sb + wt * 16 + bn;
  short8 B1[NKT], B2[NKT];   // split-bf16 weight frags: 136 regs, static
  #pragma unroll
  for (int kt = 0; kt < NKT; ++kt) {
    short8 b1, b2;
    #pragma unroll
    for (int j = 0; j < 8; ++j) {
      const float w = Wc[(size_t)(kt * 32 + q * 8 + j) * S + ncol];
      b1[j] = (short)bf_hi(w);
      b2[j] = (short)bf_hi(w - bf_hi_f(w));
    }
    B1[kt] = b1; B2[kt] = b2;
  }
  const float bcv = bcell[lane * S + ncol];
  const float wov = Wout[ncol];
  for (int idx = tid; idx < 2 * S; idx += NT)
    wg_lds[idx] = (lane > 0) ? Wcomb[(size_t)(lane - 1) * 2 * S + idx] : 0.0f;
  const float bg = (lane > 0) ? bcomb[lane - 1] : 0.0f;
  // stage/gate mapping: 32 threads per row, 16 rows; wave w owns rows 2w,2w+1
  const int grow = tid >> 5, gch = tid & 31;
  __syncthreads();   // gates on tid0's flag wait too

  float oacc[4] = {0.f, 0.f, 0.f, 0.f};

  for (int t = 0; t < T; ++t) {
    // ---- phase A: x stage (per-wave rows); no handshake here -------------
    {
      const float f0 = x[(((size_t)lane * BATCH + r0 + grow) * T + t) * FIN + gch];
      A1[grow * AS + gch] = bf_hi(f0);
      A2[grow * AS + gch] = bf_hi(f0 - bf_hi_f(f0));
    }

    // ---- phase B: fused canary-validated loads + gate + split-stage ------
    {
      float4 hv[4], pv[4];
      const float* hb = ring + ((size_t)(lane * DEPTH + ((t - 1) & 3)) * BATCH + r0 + grow) * S + gch * 4;
      const float* pb = ring + ((size_t)((lane - 1) * DEPTH + (t & 3)) * BATCH + r0 + grow) * S + gch * 4;
      const unsigned* hce = can + (((lane * 4 + ((t - 1) & 3)) * 16 + grp) * 16 + grow) * 4;
      const unsigned* pce = can + ((((lane - 1) * 4 + (t & 3)) * 16 + grp) * 16 + grow) * 4;
      const unsigned th = (unsigned)t, tp = (unsigned)(t + 1);
      u32x4 hcan, pcan, sown, scon;
      if (t > 0) {
        if (lane > 0) {
          for (;;) {
            ld_full(hv, pv, &hcan, &pcan, &sown, &scon, hb, pb, hce, pce, st_own, psc);
            bool ok = ((int)umin4(sown) >= t - 2) && ((int)umin4(scon) >= t - 3);
            ok &= alleq4(hcan, th) && alleq4(pcan, tp);
            if (ok) break;
            __builtin_amdgcn_s_sleep(1);
          }
        } else {
          for (;;) {
            ld_h(hv, &hcan, &sown, &scon, hb, hce, st_own, psc);
            bool ok = ((int)umin4(sown) >= t - 2) && ((int)umin4(scon) >= t - 3);
            ok &= alleq4(hcan, th);
            if (ok) break;
            __builtin_amdgcn_s_sleep(1);
          }
        }
      } else {
        #pragma unroll
        for (int j = 0; j < 4; ++j) hv[j] = make_float4(0.f, 0.f, 0.f, 0.f);
        if (lane > 0) {
          for (;;) {
            ld_p(pv, &pcan, &sown, &scon, pb, pce, st_own, psc);
            if (alleq4(pcan, tp)) break;
            __builtin_amdgcn_s_sleep(1);
          }
        }
      }

      if (lane > 0) {
        float gs = 0.0f;
        #pragma unroll
        for (int j = 0; j < 4; ++j) {
          const float* wh = &wg_lds[j * 128 + gch * 4];
          const float* wp = wh + S;
          gs += hv[j].x * wh[0] + hv[j].y * wh[1] + hv[j].z * wh[2] + hv[j].w * wh[3];
          gs += pv[j].x * wp[0] + pv[j].y * wp[1] + pv[j].z * wp[2] + pv[j].w * wp[3];
        }
        gs += __shfl_xor(gs, 1);  gs += __shfl_xor(gs, 2);  gs += __shfl_xor(gs, 4);
        gs += __shfl_xor(gs, 8);  gs += __shfl_xor(gs, 16);  // 32-lane row halves
        const float w = 1.0f / (1.0f + __expf(-(gs + bg)));
        #pragma unroll
        for (int j = 0; j < 4; ++j) {  // hc = p + w*(h-p)
          hv[j].x = fmaf(w, hv[j].x - pv[j].x, pv[j].x);
          hv[j].y = fmaf(w, hv[j].y - pv[j].y, pv[j].y);
          hv[j].z = fmaf(w, hv[j].z - pv[j].z, pv[j].z);
          hv[j].w = fmaf(w, hv[j].w - pv[j].w, pv[j].w);
        }
      }
      #pragma unroll
      for (int j = 0; j < 4; ++j) {
        ushort4 h4, l4;
        h4.x = bf_hi(hv[j].x); l4.x = bf_hi(hv[j].x - bf_hi_f(hv[j].x));
        h4.y = bf_hi(hv[j].y); l4.y = bf_hi(hv[j].y - bf_hi_f(hv[j].y));
        h4.z = bf_hi(hv[j].z); l4.z = bf_hi(hv[j].z - bf_hi_f(hv[j].z));
        h4.w = bf_hi(hv[j].w); l4.w = bf_hi(hv[j].w - bf_hi_f(hv[j].w));
        const int ai = grow * AS + 32 + j * 128 + gch * 4;
        *(ushort4*)&A1[ai] = h4;
        *(ushort4*)&A2[ai] = l4;
      }
    }
    __syncthreads();

    // ---- phase C: MFMA 16x16 tile, 17 K-tiles x 3 split products ----------
    f32x4 acc = {0.f, 0.f, 0.f, 0.f};
    {
      const unsigned short* ar1 = &A1[bn * AS + q * 8];
      const unsigned short* ar2 = &A2[bn * AS + q * 8];
      #pragma unroll
      for (int kt = 0; kt < NKT; ++kt) {
        const short8 a1 = *(const short8*)(ar1 + kt * 32);
        const short8 a2 = *(const short8*)(ar2 + kt * 32);
        acc = __builtin_amdgcn_mfma_f32_16x16x32_bf16(a1, B1[kt], acc, 0, 0, 0);
        acc = __builtin_amdgcn_mfma_f32_16x16x32_bf16(a1, B2[kt], acc, 0, 0, 0);
        acc = __builtin_amdgcn_mfma_f32_16x16x32_bf16(a2, B1[kt], acc, 0, 0, 0);
      }
    }

    // ---- epilogue: +bias, tanh, ring store, drain, canary+stamp publish --
    float* slot = ring + ((size_t)(lane * DEPTH + (t & 3)) * BATCH + r0) * S + sb;
    #pragma unroll
    for (int reg = 0; reg < 4; ++reg) {
      const float s2 = acc[reg] + bcv;
      const float aa = fabsf(s2), ee = __expf(2.0f * aa);
      const float tv = copysignf(1.0f - 2.0f / (ee + 1.0f), s2);
      cstore1(slot + (size_t)(q * 4 + reg) * S + wt * 16 + bn, tv);
      if (t == T - 1) oacc[reg] = tv * wov;
    }
    asm volatile("s_waitcnt vmcnt(0)" ::: "memory");  // own stores at MALL
    __syncthreads();  // ALL waves' data drained -> canary may publish
    if (tid < 16)
      cstoreu_glb(can + ((((lane * 4 + (t & 3)) * 16 + grp) * 16 + tid) * 4 + sl),
                  (unsigned)(t + 1));
    else if (tid == 16)
      cstoreu_glb(st_mine, (unsigned)(t + 1));
  }

  // ---- output: out[lane*256 + r] = h_T[r] . Wout --------------------------
  #pragma unroll
  for (int reg = 0; reg < 4; ++reg) {
    float v = oacc[reg];
    v += __shfl_xor(v, 1); v += __shfl_xor(v, 2);
    v += __shfl_xor(v, 4); v += __shfl_xor(v, 8);  // sum 16 cols of the tile
    if (bn == 0) obuf[wt * 16 + q * 4 + reg] = v;
  }
  __syncthreads();
  if (tid < 16) {
    float v = 0.0f;
    #pragma unroll
    for (int w = 0; w < 8; ++w) v += obuf[w * 16 + tid];
    cstore1(ws + OUTP_OFF + (size_t)((gid * 4 + sl) * 16 + tid), v);
  }
  asm volatile("s_waitcnt vmcnt(0)" ::: "memory");
  __syncthreads();
  if (tid == 0) cstoreu_glb(st_mine, (unsigned)(T + 1));
  if (sl == 0) {
    if (tid == 0)
      while (umin4(cld4_glb(st_own)) < (unsigned)(T + 1)) __builtin_amdgcn_s_sleep(1);
    __syncthreads();
    if (tid < 64) {
      const int sli = tid >> 4, r = tid & 15;
      fbuf[tid] = cload1(ws + OUTP_OFF + (size_t)((gid * 4 + sli) * 16 + r));
    }
    __syncthreads();
    if (tid < 16) {
      float s2 = 0.f;
      #pragma unroll
      for (int sli = 0; sli < 4; ++sli) s2 += fbuf[sli * 16 + tid];
      out[lane * BATCH + r0 + tid] = s2;
    }
  }
}

extern "C" void kernel_launch(void* const* d_in, const int* in_sizes, int n_in,
                              void* d_out, int out_size, void* d_ws, size_t ws_size,
                              hipStream_t stream) {
  (void)in_sizes; (void)n_in; (void)out_size; (void)ws_size;
  rnn_mfma<<<dim3(NWG), dim3(NT), 0, stream>>>(
      (const float*)d_in[0],   // inputs
      (const float*)d_in[1],   // W_cell
      (const float*)d_in[2],   // b_cell
      (const float*)d_in[3],   // W_comb
      (const float*)d_in[4],   // b_comb
      (const float*)d_in[5],   // W_out
      (float*)d_out,
      (float*)d_ws);
}